// Round 4
// baseline (1091.318 us; speedup 1.0000x reference)
//
#include <hip/hip_runtime.h>
#include <math.h>

#define HD 1024
#define VD 50257
#define SD 2048
#define NVB 12565          // ceil(VD/4) row-groups for vocab GEMV kernels
#define FRONT_BLOCKS 512

// ws float layout:
//   [0     .. 1024)  u2       (atomic, memset 0)
//   [1024  .. 2048)  context  (atomic, memset 0)
//   [2048  .. 2064)  barrier counters (memset 0)
//   [2304  .. 4352)  scores
//   [4352  .. 5376)  h_new
//   [5376  .. 8448)  gA = W_ih[:, :H]@emb + b_ih
//   [8448  .. 11520) gh = W_hh@h + b_hh
//   [12288 .. 12288+2*NVB) lse partials (m,s) per k_logits block

__device__ __forceinline__ float wred(float x) {
#pragma unroll
    for (int o = 32; o; o >>= 1) x += __shfl_down(x, o, 64);
    return x;  // valid in lane 0
}

// single-use grid barrier: every block calls it; counter pre-zeroed by memset.
__device__ __forceinline__ void gbar(unsigned int* cnt, unsigned int target) {
    __syncthreads();
    __threadfence();
    if (threadIdx.x == 0) {
        __hip_atomic_fetch_add(cnt, 1u, __ATOMIC_RELEASE, __HIP_MEMORY_SCOPE_AGENT);
        while (__hip_atomic_load(cnt, __ATOMIC_ACQUIRE, __HIP_MEMORY_SCOPE_AGENT) < target) {}
    }
    __syncthreads();
    __threadfence();
}

// Fused front-end: u2 | gA,gh  ->  scores  ->  softmax+context  ->  gx2+gates+h_new
__global__ __launch_bounds__(256) void k_front(
        const float* __restrict__ attn_W, const float* __restrict__ other,
        const float* __restrict__ enc, const float* __restrict__ embedding,
        const int* __restrict__ word, const float* __restrict__ h,
        const float* __restrict__ W_ih, const float* __restrict__ W_hh,
        const float* __restrict__ b_ih, const float* __restrict__ b_hh,
        float* __restrict__ ws, float* __restrict__ dout) {
    __shared__ float sm[SD];
    __shared__ float wr[8];
    __shared__ float bc;
    unsigned int* cnt = (unsigned int*)(ws + 2048);
    float* u2 = ws;
    float* context = ws + 1024;
    float* scores = ws + 2304;
    float* hnew = ws + 4352;
    float* gA = ws + 5376;
    float* gh = ws + 8448;
    const int b = blockIdx.x, t = threadIdx.x;
    const int lane = t & 63, wave = t >> 6;

    // ---- phase 1: u2 (blocks 0..31) | gA,gh (blocks 32..287) ----
    if (b < 32) {
        const int kt = b & 3, jc = b >> 2;        // 4 k-tiles x 8 j-chunks
        const int k = kt * 256 + t;
        const float* Wcol = attn_W + HD + k;
        const int j0 = jc * 128;
        float acc = 0.f;
#pragma unroll 8
        for (int j = 0; j < 128; ++j)
            acc += other[j0 + j] * Wcol[(size_t)(j0 + j) * (2 * HD)];
        atomicAdd(&u2[k], acc);
    } else if (b < 288) {
        const int i = (b - 32) * 4 + wave;
        const float4* e4 = (const float4*)(embedding + (size_t)word[0] * HD);
        const float4* h4 = (const float4*)h;
#pragma unroll
        for (int g = 0; g < 3; ++g) {
            const int row = g * HD + i;
            const float4* pa = (const float4*)(W_ih + (size_t)row * 2 * HD);
            const float4* ph = (const float4*)(W_hh + (size_t)row * HD);
            float a = 0.f, hh = 0.f;
#pragma unroll
            for (int k = lane; k < 256; k += 64) {
                float4 w1 = pa[k], w3 = ph[k];
                float4 v1 = e4[k], v3 = h4[k];
                a += w1.x * v1.x + w1.y * v1.y + w1.z * v1.z + w1.w * v1.w;
                hh += w3.x * v3.x + w3.y * v3.y + w3.z * v3.z + w3.w * v3.w;
            }
            a = wred(a); hh = wred(hh);
            if (lane == 0) {
                gA[row] = a + b_ih[row];
                gh[row] = hh + b_hh[row];
            }
        }
    }
    gbar(cnt + 0, FRONT_BLOCKS);

    // ---- phase 2: scores[s] = enc[s] . u2  (all 512 blocks, 4 rows each) ----
    {
        const int row = b * 4 + wave;
        const float4* p = (const float4*)(enc + (size_t)row * HD);
        const float4* q = (const float4*)u2;
        float acc = 0.f;
#pragma unroll
        for (int i = lane; i < 256; i += 64) {
            float4 a = p[i], c = q[i];
            acc += a.x * c.x + a.y * c.y + a.z * c.z + a.w * c.w;
        }
        acc = wred(acc);
        if (lane == 0) scores[row] = acc;
    }
    gbar(cnt + 1, FRONT_BLOCKS);

    // ---- phase 3: redundant softmax + context partials (blocks 0..127) ----
    if (b < 128) {
        float lm = -INFINITY;
        for (int i = t; i < SD; i += 256) {
            float x = scores[i];
            sm[i] = x;
            lm = fmaxf(lm, x);
        }
#pragma unroll
        for (int o = 32; o; o >>= 1) lm = fmaxf(lm, __shfl_down(lm, o, 64));
        if (lane == 0) wr[wave] = lm;
        __syncthreads();
        if (t == 0) bc = fmaxf(fmaxf(wr[0], wr[1]), fmaxf(wr[2], wr[3]));
        __syncthreads();
        const float M = bc;
        float ls = 0.f;
        for (int i = t; i < SD; i += 256) ls += __expf(sm[i] - M);
#pragma unroll
        for (int o = 32; o; o >>= 1) ls += __shfl_down(ls, o, 64);
        if (lane == 0) wr[4 + wave] = ls;
        __syncthreads();
        if (t == 0) bc = wr[4] + wr[5] + wr[6] + wr[7];
        __syncthreads();
        const float inv = 1.f / bc;
        for (int i = t; i < SD; i += 256) sm[i] = __expf(sm[i] - M) * inv;
        __syncthreads();
        if (b == 0)
            for (int i = t; i < SD; i += 256) dout[VD + HD + i] = sm[i];
        const int rc = b >> 2, ct = b & 3;   // 32 row-chunks x 4 col-tiles
        const int j = ct * 256 + t;
        const int r0 = rc * 64;
        float acc = 0.f;
#pragma unroll 4
        for (int r = 0; r < 64; ++r)
            acc += sm[r0 + r] * enc[(size_t)(r0 + r) * HD + j];
        atomicAdd(&context[j], acc);
    }
    gbar(cnt + 2, FRONT_BLOCKS);

    // ---- phase 4: gx2 = W_ih[:,H:]@context ; gates ; h_new (blocks 0..255) ----
    if (b < 256) {
        const int i = b * 4 + wave;
        const float4* c4 = (const float4*)context;
        float x2[3];
#pragma unroll
        for (int g = 0; g < 3; ++g) {
            const float4* px = (const float4*)(W_ih + (size_t)(g * HD + i) * 2 * HD + HD);
            float a = 0.f;
#pragma unroll
            for (int k = lane; k < 256; k += 64) {
                float4 w = px[k], c = c4[k];
                a += w.x * c.x + w.y * c.y + w.z * c.z + w.w * c.w;
            }
            x2[g] = wred(a);
        }
        if (lane == 0) {
            const float r = 1.f / (1.f + __expf(-(gA[i] + x2[0] + gh[i])));
            const float z = 1.f / (1.f + __expf(-(gA[HD + i] + x2[1] + gh[HD + i])));
            const float n = tanhf(gA[2 * HD + i] + x2[2] + r * gh[2 * HD + i]);
            const float hn = (1.f - z) * n + z * h[i];
            dout[VD + i] = hn;
            hnew[i] = hn;
        }
    }
}

// K2: logits[row] = out_W[row] . [h_new, context] + out_b[row]; block lse partial.
__global__ __launch_bounds__(256) void k_logits(
        const float* __restrict__ out_W, const float* __restrict__ out_b,
        const float* __restrict__ ws, float* __restrict__ part,
        float* __restrict__ dout) {
    __shared__ float4 sy[512];
    __shared__ float lgt[4];
    const int t = threadIdx.x, lane = t & 63, wave = t >> 6;
    sy[t] = ((const float4*)(ws + 4352))[t];        // h_new
    sy[t + 256] = ((const float4*)(ws + 1024))[t];  // context
    __syncthreads();
    const int row = blockIdx.x * 4 + wave;
    float logit = -INFINITY;
    if (row < VD) {
        const float4* p = (const float4*)(out_W + (size_t)row * 2 * HD);
        float acc = 0.f;
#pragma unroll
        for (int i = lane; i < 512; i += 64) {
            float4 a = p[i], c = sy[i];
            acc += a.x * c.x + a.y * c.y + a.z * c.z + a.w * c.w;
        }
        acc = wred(acc);
        if (lane == 0) {
            logit = acc + out_b[row];
            dout[row] = logit;
        }
    }
    if (lane == 0) lgt[wave] = logit;
    __syncthreads();
    if (t == 0) {
        const float m = fmaxf(fmaxf(lgt[0], lgt[1]), fmaxf(lgt[2], lgt[3]));
        float s = 0.f;
#pragma unroll
        for (int w = 0; w < 4; ++w) s += __expf(lgt[w] - m);  // exp(-inf)=0 for pads
        part[2 * blockIdx.x] = m;
        part[2 * blockIdx.x + 1] = s;
    }
}

// K3: each block redundantly reduces (m,s) partials (bit-identical order),
//     then subtracts lse from its 256 logits.
__global__ __launch_bounds__(256) void k_sub(
        float* __restrict__ dout, const float* __restrict__ part) {
    __shared__ float wm[4], wsm[4];
    __shared__ float lsef;
    const int t = threadIdx.x, lane = t & 63, wave = t >> 6;
    float m = -INFINITY, s = 0.f;
    for (int i = t; i < NVB; i += 256) {
        float m2 = part[2 * i], s2 = part[2 * i + 1];
        float M = fmaxf(m, m2);
        s = s * __expf(m - M) + s2 * __expf(m2 - M);
        m = M;
    }
#pragma unroll
    for (int o = 32; o; o >>= 1) {
        float m2 = __shfl_down(m, o, 64), s2 = __shfl_down(s, o, 64);
        float M = fmaxf(m, m2);
        s = s * __expf(m - M) + s2 * __expf(m2 - M);
        m = M;
    }
    if (lane == 0) { wm[wave] = m; wsm[wave] = s; }
    __syncthreads();
    if (t == 0) {
        float M = wm[0], S = wsm[0];
#pragma unroll
        for (int w = 1; w < 4; ++w) {
            float M2 = fmaxf(M, wm[w]);
            S = S * __expf(M - M2) + wsm[w] * __expf(wm[w] - M2);
            M = M2;
        }
        lsef = M + logf(S);
    }
    __syncthreads();
    const int v = blockIdx.x * 256 + t;
    if (v < VD) dout[v] -= lsef;
}

extern "C" void kernel_launch(void* const* d_in, const int* in_sizes, int n_in,
                              void* d_out, int out_size, void* d_ws, size_t ws_size,
                              hipStream_t stream) {
    const int* word = (const int*)d_in[0];
    const float* h = (const float*)d_in[1];
    const float* enc = (const float*)d_in[2];
    const float* embedding = (const float*)d_in[3];
    const float* attn_W = (const float*)d_in[4];
    // d_in[5] = attn_b unused: scores = enc@u2 + const; softmax shift-invariant.
    const float* other = (const float*)d_in[6];
    const float* W_ih = (const float*)d_in[7];
    const float* W_hh = (const float*)d_in[8];
    const float* b_ih = (const float*)d_in[9];
    const float* b_hh = (const float*)d_in[10];
    const float* out_W = (const float*)d_in[11];
    const float* out_b = (const float*)d_in[12];
    float* out = (float*)d_out;
    float* ws = (float*)d_ws;

    // zero u2 + context + barrier counters
    hipMemsetAsync(ws, 0, 2064 * sizeof(float), stream);
    k_front<<<FRONT_BLOCKS, 256, 0, stream>>>(attn_W, other, enc, embedding, word,
                                              h, W_ih, W_hh, b_ih, b_hh, ws, out);
    k_logits<<<NVB, 256, 0, stream>>>(out_W, out_b, ws, ws + 12288, out);
    k_sub<<<197, 256, 0, stream>>>(out, ws + 12288);
}

// Round 5
// 992.682 us; speedup vs baseline: 1.0994x; 1.0994x over previous
//
#include <hip/hip_runtime.h>
#include <math.h>

#define HD 1024
#define VD 50257
#define SD 2048
#define NVB 12565          // ceil(VD/4) row-groups for the vocab GEMV
#define FB 512             // front-end blocks (co-resident: 2 blocks/CU on 256 CUs)

// ws float layout (all write-once, no atomics except barrier counters):
//   [0     ..  8192) u2 partials (8 x 1024)
//   [8192  ..  8208) barrier counters (3 used; memset 64 B)
//   [8256  .. 10304) scores (2048)
//   [10304 .. 11328) h_new (1024)
//   [11328 .. 14400) gA = W_ih[:, :H]@emb + b_ih (3072)
//   [14400 .. 17472) gh = W_hh@h + b_hh (3072)
//   [17472 .. 18496) context final (1024)
//   [18496 .. 51264) context partials P (32 x 1024)
//   [51264 .. 51264+2*NVB) lse partials (m,s)

__device__ __forceinline__ float wred(float x) {
#pragma unroll
    for (int o = 32; o; o >>= 1) x += __shfl_down(x, o, 64);
    return x;  // valid in lane 0
}

// single-use grid barrier with sleep backoff (counter pre-zeroed by memset).
__device__ __forceinline__ void gbar(unsigned int* cnt) {
    __syncthreads();
    __threadfence();
    if (threadIdx.x == 0) {
        __hip_atomic_fetch_add(cnt, 1u, __ATOMIC_RELEASE, __HIP_MEMORY_SCOPE_AGENT);
        while (__hip_atomic_load(cnt, __ATOMIC_RELAXED, __HIP_MEMORY_SCOPE_AGENT) < FB)
            __builtin_amdgcn_s_sleep(64);   // ~1.7 us poll quantum: no coherence storm
    }
    __syncthreads();
    __threadfence();
}

// Fused front-end: {u2 partials | gA,gh} -> scores -> softmax+context -> GRU h_new
__global__ __launch_bounds__(256) void k_front(
        const float* __restrict__ attn_W, const float* __restrict__ other,
        const float* __restrict__ enc, const float* __restrict__ embedding,
        const int* __restrict__ word, const float* __restrict__ h,
        const float* __restrict__ W_ih, const float* __restrict__ W_hh,
        const float* __restrict__ b_ih, const float* __restrict__ b_hh,
        float* __restrict__ ws, float* __restrict__ dout) {
    __shared__ float4 sbuf[512];              // 8 KB, reused per phase
    __shared__ float wr[8];
    __shared__ float bc;
    float* sf = (float*)sbuf;
    unsigned int* cnt = (unsigned int*)(ws + 8192);
    float* u2p = ws;
    float* scores = ws + 8256;
    float* hnew = ws + 10304;
    float* gA = ws + 11328;
    float* gh = ws + 14400;
    float* ctxf = ws + 17472;
    float* P = ws + 18496;
    const int b = blockIdx.x, t = threadIdx.x;
    const int lane = t & 63, wave = t >> 6;

    // ---- phase 1: u2 partials (blocks 0..31) | gA,gh (blocks 32..287) ----
    if (b < 32) {
        const int kt = b & 3, jc = b >> 2;      // 4 k-tiles x 8 j-chunks
        const int k = kt * 256 + t;
        const float* Wcol = attn_W + HD + k;
        const int j0 = jc * 128;
        float acc = 0.f;
#pragma unroll 8
        for (int j = 0; j < 128; ++j)
            acc += other[j0 + j] * Wcol[(size_t)(j0 + j) * (2 * HD)];
        u2p[jc * HD + k] = acc;                 // write-once
    } else if (b < 288) {
        const int i = (b - 32) * 4 + wave;
        const float4* e4 = (const float4*)(embedding + (size_t)word[0] * HD);
        const float4* h4 = (const float4*)h;
#pragma unroll
        for (int g = 0; g < 3; ++g) {
            const int row = g * HD + i;
            const float4* pa = (const float4*)(W_ih + (size_t)row * 2 * HD);
            const float4* ph = (const float4*)(W_hh + (size_t)row * HD);
            float a = 0.f, hh = 0.f;
#pragma unroll
            for (int k = lane; k < 256; k += 64) {
                float4 w1 = pa[k], w3 = ph[k];
                float4 v1 = e4[k], v3 = h4[k];
                a += w1.x * v1.x + w1.y * v1.y + w1.z * v1.z + w1.w * v1.w;
                hh += w3.x * v3.x + w3.y * v3.y + w3.z * v3.z + w3.w * v3.w;
            }
            a = wred(a); hh = wred(hh);
            if (lane == 0) {
                gA[row] = a + b_ih[row];
                gh[row] = hh + b_hh[row];
            }
        }
    }
    gbar(cnt + 0);

    // ---- phase 2: reduce u2 partials to LDS, scores[s] = enc[s].u2 (all blocks) ----
    for (int j = t; j < HD; j += 256) {
        float s = 0.f;
#pragma unroll
        for (int p = 0; p < 8; ++p) s += u2p[p * HD + j];
        sf[j] = s;
    }
    __syncthreads();
    {
        const int row = b * 4 + wave;           // 512*4 = 2048 rows
        const float4* p = (const float4*)(enc + (size_t)row * HD);
        float acc = 0.f;
#pragma unroll
        for (int i = lane; i < 256; i += 64) {
            float4 a = p[i], c = sbuf[i];
            acc += a.x * c.x + a.y * c.y + a.z * c.z + a.w * c.w;
        }
        acc = wred(acc);
        if (lane == 0) scores[row] = acc;
    }
    gbar(cnt + 1);

    // ---- phase 3: redundant softmax + context partials (blocks 0..127) ----
    if (b < 128) {
        float lm = -INFINITY;
        for (int i = t; i < SD; i += 256) {
            float x = scores[i];
            sf[i] = x;
            lm = fmaxf(lm, x);
        }
#pragma unroll
        for (int o = 32; o; o >>= 1) lm = fmaxf(lm, __shfl_down(lm, o, 64));
        if (lane == 0) wr[wave] = lm;
        __syncthreads();
        if (t == 0) bc = fmaxf(fmaxf(wr[0], wr[1]), fmaxf(wr[2], wr[3]));
        __syncthreads();
        const float M = bc;
        float ls = 0.f;
        for (int i = t; i < SD; i += 256) ls += __expf(sf[i] - M);
#pragma unroll
        for (int o = 32; o; o >>= 1) ls += __shfl_down(ls, o, 64);
        if (lane == 0) wr[4 + wave] = ls;
        __syncthreads();
        if (t == 0) bc = wr[4] + wr[5] + wr[6] + wr[7];
        __syncthreads();
        const float inv = 1.f / bc;
        for (int i = t; i < SD; i += 256) sf[i] = __expf(sf[i] - M) * inv;
        __syncthreads();
        if (b == 0)
            for (int i = t; i < SD; i += 256) dout[VD + HD + i] = sf[i];
        const int rc = b >> 2, ct = b & 3;      // 32 row-chunks x 4 col-tiles
        const int j = ct * 256 + t;
        const int r0 = rc * 64;
        float acc = 0.f;
#pragma unroll 4
        for (int r = 0; r < 64; ++r)
            acc += sf[r0 + r] * enc[(size_t)(r0 + r) * HD + j];
        P[rc * HD + j] = acc;                   // write-once
    }
    gbar(cnt + 2);

    // ---- phase 4: context reduce + gx2 + gates + h_new (blocks 0..255) ----
    if (b < 256) {
        for (int j = t; j < HD; j += 256) {
            float c = 0.f;
#pragma unroll
            for (int rc = 0; rc < 32; ++rc) c += P[rc * HD + j];
            sf[j] = c;
        }
        __syncthreads();
        if (t < 4) ctxf[b * 4 + t] = sf[b * 4 + t];   // final context, write-once
        const int i = b * 4 + wave;
        float x2[3];
#pragma unroll
        for (int g = 0; g < 3; ++g) {
            const float4* px = (const float4*)(W_ih + (size_t)(g * HD + i) * 2 * HD + HD);
            float a = 0.f;
#pragma unroll
            for (int k = lane; k < 256; k += 64) {
                float4 w = px[k], c = sbuf[k];
                a += w.x * c.x + w.y * c.y + w.z * c.z + w.w * c.w;
            }
            x2[g] = wred(a);
        }
        if (lane == 0) {
            const float r = 1.f / (1.f + __expf(-(gA[i] + x2[0] + gh[i])));
            const float z = 1.f / (1.f + __expf(-(gA[HD + i] + x2[1] + gh[HD + i])));
            const float n = tanhf(gA[2 * HD + i] + x2[2] + r * gh[2 * HD + i]);
            const float hn = (1.f - z) * n + z * h[i];
            dout[VD + i] = hn;
            hnew[i] = hn;
        }
    }
}

// K2: logits[row] = out_W[row] . [h_new, context] + out_b[row]; per-block lse partial.
__global__ __launch_bounds__(256) void k_logits(
        const float* __restrict__ out_W, const float* __restrict__ out_b,
        const float* __restrict__ ws, float* __restrict__ part,
        float* __restrict__ dout) {
    __shared__ float4 sy[512];
    __shared__ float lgt[4];
    const int t = threadIdx.x, lane = t & 63, wave = t >> 6;
    sy[t] = ((const float4*)(ws + 10304))[t];        // h_new
    sy[t + 256] = ((const float4*)(ws + 17472))[t];  // context
    __syncthreads();
    const int row = blockIdx.x * 4 + wave;
    float logit = -INFINITY;
    if (row < VD) {
        const float4* p = (const float4*)(out_W + (size_t)row * 2 * HD);
        float acc = 0.f;
#pragma unroll
        for (int i = lane; i < 512; i += 64) {
            float4 a = p[i], c = sy[i];
            acc += a.x * c.x + a.y * c.y + a.z * c.z + a.w * c.w;
        }
        acc = wred(acc);
        if (lane == 0) {
            logit = acc + out_b[row];
            dout[row] = logit;
        }
    }
    if (lane == 0) lgt[wave] = logit;
    __syncthreads();
    if (t == 0) {
        const float m = fmaxf(fmaxf(lgt[0], lgt[1]), fmaxf(lgt[2], lgt[3]));
        float s = 0.f;
#pragma unroll
        for (int w = 0; w < 4; ++w) s += __expf(lgt[w] - m);  // exp(-inf)=0 for pads
        part[2 * blockIdx.x] = m;
        part[2 * blockIdx.x + 1] = s;
    }
}

// K3: each block redundantly reduces (m,s) partials (bit-identical order),
//     then subtracts lse from its 256 logits.
__global__ __launch_bounds__(256) void k_sub(
        float* __restrict__ dout, const float* __restrict__ part) {
    __shared__ float wm[4], wsm[4];
    __shared__ float lsef;
    const int t = threadIdx.x, lane = t & 63, wave = t >> 6;
    float m = -INFINITY, s = 0.f;
    for (int i = t; i < NVB; i += 256) {
        float m2 = part[2 * i], s2 = part[2 * i + 1];
        float M = fmaxf(m, m2);
        s = s * __expf(m - M) + s2 * __expf(m2 - M);
        m = M;
    }
#pragma unroll
    for (int o = 32; o; o >>= 1) {
        float m2 = __shfl_down(m, o, 64), s2 = __shfl_down(s, o, 64);
        float M = fmaxf(m, m2);
        s = s * __expf(m - M) + s2 * __expf(m2 - M);
        m = M;
    }
    if (lane == 0) { wm[wave] = m; wsm[wave] = s; }
    __syncthreads();
    if (t == 0) {
        float M = wm[0], S = wsm[0];
#pragma unroll
        for (int w = 1; w < 4; ++w) {
            float M2 = fmaxf(M, wm[w]);
            S = S * __expf(M - M2) + wsm[w] * __expf(wm[w] - M2);
            M = M2;
        }
        lsef = M + logf(S);
    }
    __syncthreads();
    const int v = blockIdx.x * 256 + t;
    if (v < VD) dout[v] -= lsef;
}

extern "C" void kernel_launch(void* const* d_in, const int* in_sizes, int n_in,
                              void* d_out, int out_size, void* d_ws, size_t ws_size,
                              hipStream_t stream) {
    const int* word = (const int*)d_in[0];
    const float* h = (const float*)d_in[1];
    const float* enc = (const float*)d_in[2];
    const float* embedding = (const float*)d_in[3];
    const float* attn_W = (const float*)d_in[4];
    // d_in[5] = attn_b unused: scores = enc@u2 + const; softmax shift-invariant.
    const float* other = (const float*)d_in[6];
    const float* W_ih = (const float*)d_in[7];
    const float* W_hh = (const float*)d_in[8];
    const float* b_ih = (const float*)d_in[9];
    const float* b_hh = (const float*)d_in[10];
    const float* out_W = (const float*)d_in[11];
    const float* out_b = (const float*)d_in[12];
    float* out = (float*)d_out;
    float* ws = (float*)d_ws;

    hipMemsetAsync(ws + 8192, 0, 64, stream);   // barrier counters only
    k_front<<<FB, 256, 0, stream>>>(attn_W, other, enc, embedding, word,
                                    h, W_ih, W_hh, b_ih, b_hh, ws, out);
    k_logits<<<NVB, 256, 0, stream>>>(out_W, out_b, ws, ws + 51264, out);
    k_sub<<<197, 256, 0, stream>>>(out, ws + 51264);
}